// Round 8
// baseline (1048.150 us; speedup 1.0000x reference)
//
#include <hip/hip_runtime.h>

// Problem dims
#define B_   256
#define N_   16000
#define C_   32
#define K_   64
#define T_   124
#define NJ   125      // 128-sample half-window block sums, j = 0..124
#define HID_ 50
#define OUT_ 10

// Exact single f32 ops (prevent fma contraction / reassociation).
__device__ __forceinline__ float fadd(float a, float b) { return __fadd_rn(a, b); }
__device__ __forceinline__ float fmul(float a, float b) { return __fmul_rn(a, b); }
__device__ __forceinline__ float fsub(float a, float b) { return __fsub_rn(a, b); }

// ---------------------------------------------------------------------------
// Fully fused, one 256-thread block per batch element. Zero d_ws use.
// ALL ARITHMETIC IS FLOAT32 IN NUMPY'S ORDER (rounds 6/7 post-mortem: the
// checker's np reference is float32-faithful; a f64 pipeline flips ~2-5 of
// the 10.2M near-threshold AN decisions -> err 1.0 every time).
//
// Order model of the np reference:
//  - conv (SAME pad_lo=31, correlation): BLAS-style sequential-k f32 FMA
//  - relu, then 256-window sum = numpy pairwise: P256 = P128(lo)+P128(hi),
//    P128 = 8 stride-8 slot accumulators (16 seq adds) combined
//    ((r0+r1)+(r2+r3))+((r4+r5)+(r6+r7)); mean = /256 (exact pow2)
//  - AN: (env*scale - 0.5) > 0, scales = np.linspace f64 -> f32 cast
//  - matmuls: sequential-k chain; spike inputs are 0/1 so products are exact
//  - LIF: m = 0.95f*mem + cur (separate mul/add); spk = (m-1>0); mem = m-spk
// Outputs float32: spk_rec then mem_rec, each [B,T,OUT] flat.
// ---------------------------------------------------------------------------
__global__ __launch_bounds__(256) void fused8(const float* __restrict__ audio,
                                              const float* __restrict__ gt,
                                              const float* __restrict__ Wb,
                                              const float* __restrict__ Wic,
                                              const float* __restrict__ Wac,
                                              float* __restrict__ out) {
    __shared__ __align__(16) float abuf[1152];     //  4,608 B audio tile + halo
    __shared__ __align__(16) float ybuf[4][1024];  // 16,384 B relu'd conv, per wave
    __shared__ float S[C_][NJ];                    // 16,000 B 128-block pairwise sums
    __shared__ float sWb[HID_ * 321];              // 64,200 B (stride 321: 2-way banks)
    __shared__ float sWic[HID_ * 51];              // 10,200 B
    __shared__ float sWac[OUT_ * 51];              //  2,040 B
    __shared__ float spkan[C_ * 10];               //  1,280 B
    __shared__ float spkb[HID_], spkic[HID_];      //    400 B
    // total ~115 KB

    const int b = blockIdx.x, tid = threadIdx.x;
    const int w = tid >> 6, lane = tid & 63;

    // ---- stage weights (exact f32 copies) ----
    for (int i = tid; i < HID_ * 320; i += 256) {
        int r = i / 320;
        sWb[r * 321 + (i - r * 320)] = Wb[i];
    }
    for (int i = tid; i < HID_ * HID_; i += 256) {
        int r = i / 50;
        sWic[r * 51 + (i - r * 50)] = Wic[i];
    }
    for (int i = tid; i < OUT_ * HID_; i += 256) {
        int r = i / 50;
        sWac[r * 51 + (i - r * 50)] = Wac[i];
    }

    const float* arow = audio + (size_t)b * N_;

    // ---- Phase A: conv (f32 fma chain) + relu + numpy-pairwise block sums ----
    for (int g = 0; g < 16; ++g) {
        __syncthreads();                          // prior tile fully consumed
        const int origin = (g << 10) - 32;
        for (int i = tid; i < 1152; i += 256) {
            int gi = origin + i;
            abuf[i] = (gi >= 0 && gi < N_) ? arow[gi] : 0.0f;
        }
        __syncthreads();
        for (int ci = 0; ci < 8; ++ci) {
            const int c = (w << 3) + ci;          // wave w owns channels 8w..8w+7
            float kreg[K_];
#pragma unroll
            for (int k = 0; k < K_; ++k) kreg[k] = gt[(c << 6) + k];
            for (int pp = 0; pp < 4; ++pp) {
                const int Lb = (pp << 8) + (lane << 2);
                float y0 = 0.0f, y1 = 0.0f, y2 = 0.0f, y3 = 0.0f;
#pragma unroll
                for (int q = 0; q < 17; ++q) {    // k ascending per output: BLAS order
                    float4 A4 = *(const float4*)(abuf + Lb + (q << 2));
                    const float av[4] = {A4.x, A4.y, A4.z, A4.w};
#pragma unroll
                    for (int e = 0; e < 4; ++e) {
                        const int kb = (q << 2) + e - 1;   // k for output d=0
                        if (kb     >= 0 && kb     < K_) y0 = fmaf(av[e], kreg[kb    ], y0);
                        if (kb - 1 >= 0 && kb - 1 < K_) y1 = fmaf(av[e], kreg[kb - 1], y1);
                        if (kb - 2 >= 0 && kb - 2 < K_) y2 = fmaf(av[e], kreg[kb - 2], y2);
                        if (kb - 3 >= 0 && kb - 3 < K_) y3 = fmaf(av[e], kreg[kb - 3], y3);
                    }
                }
                float4 z;
                z.x = fmaxf(y0, 0.0f); z.y = fmaxf(y1, 0.0f);
                z.z = fmaxf(y2, 0.0f); z.w = fmaxf(y3, 0.0f);
                *(float4*)(&ybuf[w][(pp << 8) + (lane << 2)]) = z;
            }
            __syncthreads();                      // ybuf writes visible (paranoia)
            // numpy pairwise-128: lane = (blk8, slot j); r = seq sum of 16
            // stride-8 elements (ascending), then ((r0+r1)+(r2+r3))+((r4+r5)+(r6+r7))
            {
                const int blk8 = lane >> 3, j = lane & 7;
                const float* yb = &ybuf[w][(blk8 << 7) + j];
                float r = yb[0];
#pragma unroll
                for (int m = 1; m < 16; ++m) r = fadd(r, yb[m << 3]);
                float v = fadd(r, __shfl_xor(r, 1));   // f32 add commutative: exact
                v = fadd(v, __shfl_xor(v, 2));
                v = fadd(v, __shfl_xor(v, 4));
                const int jg = (g << 3) + blk8;
                if (j == 0 && jg < NJ) S[c][jg] = v;
            }
            __syncthreads();                      // before next ci reuses ybuf
        }
    }
    __syncthreads();

    // ---- Phase B: 124 sequential LIF steps, all f32, numpy order ----
    float memb_r = 0.0f, memic_r = 0.0f, memac_r = 0.0f;  // thread-owned state

    for (int t = 0; t < T_; ++t) {
        for (int i = tid; i < C_ * 10; i += 256) {        // AuditoryNerve
            int c = i / 10, s = i - c * 10;
            // window sum = P128(t) + P128(t+1); mean = /256 (exact)
            float env = fmul(fadd(S[c][t], S[c][t + 1]), 0.00390625f);
            // np.linspace(0.5,1.5,10): f64 compute -> f32 cast; endpoint exact
            float sf = (s == 9) ? 1.5f : (float)(0.5 + (double)s * (1.0 / 9.0));
            spkan[i] = (fsub(fmul(env, sf), 0.5f) > 0.0f) ? 1.0f : 0.0f;
        }
        __syncthreads();
        if (tid < HID_) {                                 // Bushy: seq k=0..319
            const float* wr = sWb + tid * 321;
            float acc = 0.0f;
            for (int i = 0; i < 320; ++i) acc = fadd(acc, fmul(spkan[i], wr[i]));
            float m = fadd(fmul(0.95f, memb_r), acc);
            float sp = (fsub(m, 1.0f) > 0.0f) ? 1.0f : 0.0f;
            memb_r = fsub(m, sp);
            spkb[tid] = sp;
        }
        __syncthreads();
        if (tid < HID_) {                                 // InferiorColliculus
            const float* wr = sWic + tid * 51;
            float acc = 0.0f;
#pragma unroll
            for (int gg = 0; gg < HID_; ++gg) acc = fadd(acc, fmul(spkb[gg], wr[gg]));
            float m = fadd(fmul(0.95f, memic_r), acc);
            float sp = (fsub(m, 1.0f) > 0.0f) ? 1.0f : 0.0f;
            memic_r = fsub(m, sp);
            spkic[tid] = sp;
        }
        __syncthreads();
        if (tid < OUT_) {                                 // AudioCortex + stores
            const float* wr = sWac + tid * 51;
            float acc = 0.0f;
#pragma unroll
            for (int gg = 0; gg < HID_; ++gg) acc = fadd(acc, fmul(spkic[gg], wr[gg]));
            float m = fadd(fmul(0.95f, memac_r), acc);
            float sp = (fsub(m, 1.0f) > 0.0f) ? 1.0f : 0.0f;
            float mo = fsub(m, sp);
            memac_r = mo;
            size_t base = ((size_t)b * T_ + t) * OUT_ + tid;
            out[base] = sp;
            out[(size_t)(B_ * T_ * OUT_) + base] = mo;
        }
        __syncthreads();
    }
}

// ---------------------------------------------------------------------------
extern "C" void kernel_launch(void* const* d_in, const int* in_sizes, int n_in,
                              void* d_out, int out_size, void* d_ws, size_t ws_size,
                              hipStream_t stream) {
    (void)in_sizes; (void)n_in; (void)out_size; (void)d_ws; (void)ws_size;
    fused8<<<dim3(B_), dim3(256), 0, stream>>>((const float*)d_in[0],
                                               (const float*)d_in[1],
                                               (const float*)d_in[2],
                                               (const float*)d_in[3],
                                               (const float*)d_in[4],
                                               (float*)d_out);
}

// Round 9
// 968.010 us; speedup vs baseline: 1.0828x; 1.0828x over previous
//
#include <hip/hip_runtime.h>

// Problem dims
#define B_   256
#define N_   16000
#define C_   32
#define K_   64
#define T_   124
#define NJ   125      // 128-sample half-window block sums, j = 0..124
#define HID_ 50
#define OUT_ 10

typedef unsigned int u32;

// Exact single f32 ops (prevent fma contraction / reassociation).
__device__ __forceinline__ float fadd(float a, float b) { return __fadd_rn(a, b); }
__device__ __forceinline__ float fmul(float a, float b) { return __fmul_rn(a, b); }
__device__ __forceinline__ float fsub(float a, float b) { return __fsub_rn(a, b); }

// ---------------------------------------------------------------------------
// Kernel A: conv (SAME pad_lo=31, correlation, sequential-k f32 FMA) + relu +
// numpy-pairwise 128-block sums -> Sg[b][c][j] in global scratch (f32).
// Grid (B, 8): each block does 2 audio segments of 1024 samples; wave w owns
// channels 8w..8w+7. Summation structure byte-identical to the round-8
// passing kernel; ybuf stride 128->132 removes the 8-way stride-8 bank
// conflict in the reduction (132*4 = 528 = 33*16 keeps float4 writes aligned).
// ---------------------------------------------------------------------------
__global__ __launch_bounds__(256, 4) void convA(const float* __restrict__ audio,
                                                const float* __restrict__ gt,
                                                float* __restrict__ Sg) {
    __shared__ __align__(16) float abuf[1152];
    __shared__ __align__(16) float ybuf[4][8 * 132];

    const int b = blockIdx.x, gg = blockIdx.y;
    const int tid = threadIdx.x, w = tid >> 6, lane = tid & 63;
    const float* arow = audio + (size_t)b * N_;

    for (int gs = 0; gs < 2; ++gs) {
        const int g = gg * 2 + gs;
        __syncthreads();
        const int origin = (g << 10) - 32;
        for (int i = tid; i < 1152; i += 256) {
            int gi = origin + i;
            abuf[i] = (gi >= 0 && gi < N_) ? arow[gi] : 0.0f;
        }
        __syncthreads();
        for (int ci = 0; ci < 8; ++ci) {
            const int c = (w << 3) + ci;
            float kreg[K_];
#pragma unroll
            for (int k = 0; k < K_; ++k) kreg[k] = gt[(c << 6) + k];
            for (int pp = 0; pp < 4; ++pp) {
                const int Lb = (pp << 8) + (lane << 2);
                float y0 = 0.0f, y1 = 0.0f, y2 = 0.0f, y3 = 0.0f;
#pragma unroll
                for (int q = 0; q < 17; ++q) {    // k ascending: BLAS order
                    float4 A4 = *(const float4*)(abuf + Lb + (q << 2));
                    const float av[4] = {A4.x, A4.y, A4.z, A4.w};
#pragma unroll
                    for (int e = 0; e < 4; ++e) {
                        const int kb = (q << 2) + e - 1;
                        if (kb     >= 0 && kb     < K_) y0 = fmaf(av[e], kreg[kb    ], y0);
                        if (kb - 1 >= 0 && kb - 1 < K_) y1 = fmaf(av[e], kreg[kb - 1], y1);
                        if (kb - 2 >= 0 && kb - 2 < K_) y2 = fmaf(av[e], kreg[kb - 2], y2);
                        if (kb - 3 >= 0 && kb - 3 < K_) y3 = fmaf(av[e], kreg[kb - 3], y3);
                    }
                }
                float4 z;
                z.x = fmaxf(y0, 0.0f); z.y = fmaxf(y1, 0.0f);
                z.z = fmaxf(y2, 0.0f); z.w = fmaxf(y3, 0.0f);
                const int blk = (pp << 1) + (lane >> 5);
                const int posin = (lane & 31) << 2;
                *(float4*)(&ybuf[w][blk * 132 + posin]) = z;
            }
            __syncthreads();
            // numpy pairwise-128: r = seq sum of 16 stride-8 elems, then
            // ((r0+r1)+(r2+r3))+((r4+r5)+(r6+r7)) via commutative xor-shuffles
            {
                const int blk8 = lane >> 3, j = lane & 7;
                const float* yb = &ybuf[w][blk8 * 132 + j];
                float r = yb[0];
#pragma unroll
                for (int m = 1; m < 16; ++m) r = fadd(r, yb[m << 3]);
                float v = fadd(r, __shfl_xor(r, 1));
                v = fadd(v, __shfl_xor(v, 2));
                v = fadd(v, __shfl_xor(v, 4));
                const int jg = (g << 3) + blk8;
                if (j == 0 && jg < NJ) Sg[((size_t)b * C_ + c) * NJ + jg] = v;
            }
            __syncthreads();
        }
    }
}

// ---------------------------------------------------------------------------
// Kernel B: SNN. AN spikes have no recurrence -> precompute all 124x320 as
// bitmasks; the 6200 independent (t,h) Bushy chains run in parallel on 256
// threads (bit-exact: fadd(acc, bit ? w : +0.f) == fadd(acc, fmul(s,w));
// from a +0 start acc never becomes -0, and the select injects +0).
// Then a short sequential 124-step LIF tail (Bushy->IC->AC) on wave 0.
// Grid 256 (one block per b), 256 threads. LDS ~107 KB.
// ---------------------------------------------------------------------------
__global__ __launch_bounds__(256) void snnB(const float* __restrict__ Sg,
                                            const float* __restrict__ Wb,
                                            const float* __restrict__ Wic,
                                            const float* __restrict__ Wac,
                                            float* __restrict__ out) {
    __shared__ float sWb[HID_ * 321];      // 64,200 B (321%32==1: banks spread)
    __shared__ float sWic[HID_ * 51];      // 10,200 B
    __shared__ float sWac[OUT_ * 51];      //  2,040 B
    __shared__ u32   mask[T_ * 10];        //  4,960 B  (AN spike bits per step)
    __shared__ float cur[T_ * HID_];       // 24,800 B  (Bushy pre-currents)
    __shared__ float spkb[HID_], spkic[HID_];

    const int b = blockIdx.x, tid = threadIdx.x;

    for (int i = tid; i < HID_ * 320; i += 256) {
        int r = i / 320;
        sWb[r * 321 + (i - r * 320)] = Wb[i];
    }
    for (int i = tid; i < HID_ * HID_; i += 256) {
        int r = i / 50;
        sWic[r * 51 + (i - r * 50)] = Wic[i];
    }
    for (int i = tid; i < OUT_ * HID_; i += 256) {
        int r = i / 50;
        sWac[r * 51 + (i - r * 50)] = Wac[i];
    }

    // ---- AN spike bitmasks: word (t, wd) covers i in [32wd, 32wd+32)
    const float* Sb = Sg + (size_t)b * C_ * NJ;
    for (int idx = tid; idx < T_ * 10; idx += 256) {
        int t = idx / 10, wd = idx - t * 10;
        u32 m = 0;
        int c_prev = -1;
        float env = 0.0f;
        for (int k = 0; k < 32; ++k) {
            int i = wd * 32 + k;
            int c = i / 10, s = i - c * 10;
            if (c != c_prev) {
                env = fmul(fadd(Sb[c * NJ + t], Sb[c * NJ + t + 1]), 0.00390625f);
                c_prev = c;
            }
            float sf = (s == 9) ? 1.5f : (float)(0.5 + (double)s * (1.0 / 9.0));
            if (fsub(fmul(env, sf), 0.5f) > 0.0f) m |= (1u << k);
        }
        mask[idx] = m;
    }
    __syncthreads();

    // ---- parallel Bushy currents: 6200 independent sequential-k chains
    for (int idx = tid; idx < T_ * HID_; idx += 256) {
        int t = idx / 50, h = idx - t * 50;
        const float* wr = sWb + h * 321;
        const u32*   mk = mask + t * 10;
        float acc = 0.0f;
#pragma unroll 8
        for (int i = 0; i < 320; ++i) {
            u32 bit = (mk[i >> 5] >> (i & 31)) & 1u;
            acc = fadd(acc, bit ? wr[i] : 0.0f);
        }
        cur[idx] = acc;
    }
    __syncthreads();

    // ---- sequential tail on wave 0 (single wave: no __syncthreads inside)
    if (tid < 64) {
        float memb = 0.0f, memic = 0.0f, memac = 0.0f;
        for (int t = 0; t < T_; ++t) {
            if (tid < HID_) {                         // Bushy LIF
                float m = fadd(fmul(0.95f, memb), cur[t * 50 + tid]);
                float sp = (fsub(m, 1.0f) > 0.0f) ? 1.0f : 0.0f;
                memb = fsub(m, sp);
                spkb[tid] = sp;
            }
            if (tid < HID_) {                         // InferiorColliculus
                const float* wr = sWic + tid * 51;
                float acc = 0.0f;
#pragma unroll
                for (int g = 0; g < HID_; ++g) acc = fadd(acc, fmul(spkb[g], wr[g]));
                float m = fadd(fmul(0.95f, memic), acc);
                float sp = (fsub(m, 1.0f) > 0.0f) ? 1.0f : 0.0f;
                memic = fsub(m, sp);
                spkic[tid] = sp;
            }
            if (tid < OUT_) {                         // AudioCortex + stores
                const float* wr = sWac + tid * 51;
                float acc = 0.0f;
#pragma unroll
                for (int g = 0; g < HID_; ++g) acc = fadd(acc, fmul(spkic[g], wr[g]));
                float m = fadd(fmul(0.95f, memac), acc);
                float sp = (fsub(m, 1.0f) > 0.0f) ? 1.0f : 0.0f;
                float mo = fsub(m, sp);
                memac = mo;
                size_t base = ((size_t)b * T_ + t) * OUT_ + tid;
                out[base] = sp;
                out[(size_t)(B_ * T_ * OUT_) + base] = mo;
            }
        }
    }
}

// ---------------------------------------------------------------------------
extern "C" void kernel_launch(void* const* d_in, const int* in_sizes, int n_in,
                              void* d_out, int out_size, void* d_ws, size_t ws_size,
                              hipStream_t stream) {
    (void)in_sizes; (void)n_in; (void)out_size; (void)ws_size;
    const float* audio = (const float*)d_in[0];
    const float* gt    = (const float*)d_in[1];
    const float* Wb    = (const float*)d_in[2];
    const float* Wic   = (const float*)d_in[3];
    const float* Wac   = (const float*)d_in[4];

    float* Sg = (float*)d_ws;   // needs 256*32*125*4 = 4,096,000 B of ws

    convA<<<dim3(B_, 8), dim3(256), 0, stream>>>(audio, gt, Sg);
    snnB<<<dim3(B_), dim3(256), 0, stream>>>(Sg, Wb, Wic, Wac, (float*)d_out);
}